// Round 2
// baseline (903.910 us; speedup 1.0000x reference)
//
#include <hip/hip_runtime.h>

#define NN 50000
#define KSEQ 20
#define HN_OFF 6400000   // N*128
#define CN_OFF 12800000  // 2*N*128

using short8 = __attribute__((ext_vector_type(8))) short;
using f32x4  = __attribute__((ext_vector_type(4))) float;

__device__ __forceinline__ unsigned short f2bf(float f) {
    unsigned int u = __float_as_uint(f);
    return (unsigned short)((u + 0x7FFFu + ((u >> 16) & 1u)) >> 16);  // RNE
}
__device__ __forceinline__ float exp2x(float x) { float r; asm("v_exp_f32 %0, %1" : "=v"(r) : "v"(x)); return r; }
__device__ __forceinline__ float rcpx(float x)  { float r; asm("v_rcp_f32 %0, %1" : "=v"(r) : "v"(x)); return r; }

#define L2E 1.4426950408889634f
// sigmoid(x) = 1/(1+2^(-x*log2e)); inf-safe without clamps
__device__ __forceinline__ float sigx(float x) {
    return rcpx(1.f + exp2x(-L2E * x));
}
// tanh(x) = 1 - 2/(1+2^(2x*log2e)); inf-safe without clamps
__device__ __forceinline__ float tanhx(float x) {
    float r = rcpx(1.f + exp2x((2.f * L2E) * x));
    return fmaf(-2.f, r, 1.f);
}

// ---- prep: bf16 weight packs (+transposes) and bias sum ----
__global__ void prep_kernel(const float* __restrict__ Wp, const float* __restrict__ W,
                            const float* __restrict__ Wih, const float* __restrict__ Whh,
                            const float* __restrict__ bih, const float* __restrict__ bhh,
                            unsigned short* __restrict__ Wih_b, unsigned short* __restrict__ Whh_b,
                            unsigned short* __restrict__ Wpt, unsigned short* __restrict__ Wtt,
                            float* __restrict__ bsum) {
    int tid = blockIdx.x * blockDim.x + threadIdx.x;
    if (tid < 65536) { Wih_b[tid] = f2bf(Wih[tid]); return; }
    tid -= 65536;
    if (tid < 65536) { Whh_b[tid] = f2bf(Whh[tid]); return; }
    tid -= 65536;
    if (tid < 32768) { int j = tid >> 8, k = tid & 255; Wpt[tid] = f2bf(Wp[k * 128 + j]); return; }
    tid -= 32768;
    if (tid < 32768) { int j = tid >> 8, k = tid & 255; Wtt[tid] = f2bf(W[k * 128 + j]); return; }
    tid -= 32768;
    if (tid < 512) { bsum[tid] = bih[tid] + bhh[tid]; }
}

// ---- K1: hp = bf16(h @ W_past), 32 rows/block, 8 waves (16 cols each) ----
__global__ __launch_bounds__(512, 2) void hp_kernel(const float* __restrict__ h,
                                                    const unsigned short* __restrict__ Wpt,
                                                    unsigned short* __restrict__ hp_bf) {
    __shared__ __align__(16) unsigned char smem[32 * 512];  // 32 rows x 256 bf16 (swizzled)
    const int tid = threadIdx.x;
    const int w = tid >> 6, l = tid & 63;
    const int l15 = l & 15, lq = l >> 4;
    const int base = blockIdx.x * 32;

#pragma unroll
    for (int i = 0; i < 4; ++i) {
        int chunk = tid + 512 * i;
        int row = chunk >> 6, kc = chunk & 63;
        int grow = base + row;
        float4 v = make_float4(0.f, 0.f, 0.f, 0.f);
        if (grow < NN) v = *(const float4*)(h + (size_t)grow * 256 + kc * 4);
        ushort4 bv = make_ushort4(f2bf(v.x), f2bf(v.y), f2bf(v.z), f2bf(v.w));
        int off = (row * 512 + kc * 8) ^ ((row & 7) << 4);
        *(ushort4*)(smem + off) = bv;
    }
    __syncthreads();

    const int jb = w * 16 + l15;
    short8 bf[8];
#pragma unroll
    for (int kt = 0; kt < 8; ++kt)
        bf[kt] = *(const short8*)((const unsigned char*)Wpt + jb * 512 + kt * 64 + lq * 16);

    f32x4 acc[2];
    acc[0] = (f32x4){0.f, 0.f, 0.f, 0.f};
    acc[1] = (f32x4){0.f, 0.f, 0.f, 0.f};
#pragma unroll
    for (int kt = 0; kt < 8; ++kt) {
#pragma unroll
        for (int rt = 0; rt < 2; ++rt) {
            int arow = rt * 16 + l15;
            int off = (arow * 512 + kt * 64 + lq * 16) ^ ((arow & 7) << 4);
            short8 a = *(const short8*)(smem + off);
            acc[rt] = __builtin_amdgcn_mfma_f32_16x16x32_bf16(a, bf[kt], acc[rt], 0, 0, 0);
        }
    }
#pragma unroll
    for (int rt = 0; rt < 2; ++rt)
#pragma unroll
        for (int r = 0; r < 4; ++r) {
            int row = rt * 16 + lq * 4 + r;
            int grow = base + row;
            if (grow < NN) hp_bf[(size_t)grow * 128 + w * 16 + l15] = f2bf(acc[rt][r]);
        }
}

// ---- K2: fused 20-step LSTM + output GEMM. 32 rows/block, 16 waves.
// Wave pair (b, 8+b): waves 0..7 own gates (i,f), waves 8..15 own (g,o),
// 16 cols each. sigma(i),sigma(f) exchanged via LDS (fp32).
// LDS layout (64KB): xbuf0 @0, xbuf1 @8192, hbuf0 @16384, hbuf1 @24576, sbuf @32768 (32KB)
template<int J, bool SKIP_H, bool LAST>
__device__ __forceinline__ void lstm_step(
    unsigned char* lds, const int p, const int b, const int lq, const int l15,
    const int (&aoff)[2][4], const short8 (&bw)[2][8],
    const float bi0, const float bi1, f32x4 (&cst)[2],
    const unsigned short* __restrict__ hp_bf, const int nextIdx,
    const int xw_off, const int base, float* __restrict__ out)
{
    constexpr int XB = (J & 1) * 8192;
    constexpr int XN = ((J & 1) ^ 1) * 8192;
    constexpr int HB = 16384 + (J & 1) * 8192;
    constexpr int HN = 16384 + ((J & 1) ^ 1) * 8192;

    // issue next gather BEFORE the barrier (global read, no ordering constraint)
    uint4 vnext;
    if (p == 0)
        vnext = *(const uint4*)((const unsigned char*)hp_bf + (size_t)nextIdx * 256 + l15 * 16);

    __syncthreads();  // B_main: xbuf[J&1], hbuf[J&1] ready

    f32x4 acc[2][2];
#pragma unroll
    for (int rt = 0; rt < 2; ++rt) {
        acc[0][rt] = (f32x4){bi0, bi0, bi0, bi0};
        acc[1][rt] = (f32x4){bi1, bi1, bi1, bi1};
    }
#pragma unroll
    for (int kt = 0; kt < 4; ++kt)
#pragma unroll
        for (int rt = 0; rt < 2; ++rt) {
            short8 a = *(const short8*)(lds + XB + aoff[rt][kt]);
            acc[0][rt] = __builtin_amdgcn_mfma_f32_16x16x32_bf16(a, bw[0][kt], acc[0][rt], 0, 0, 0);
            acc[1][rt] = __builtin_amdgcn_mfma_f32_16x16x32_bf16(a, bw[1][kt], acc[1][rt], 0, 0, 0);
        }
    if (!SKIP_H) {
#pragma unroll
        for (int kt = 0; kt < 4; ++kt)
#pragma unroll
            for (int rt = 0; rt < 2; ++rt) {
                short8 a = *(const short8*)(lds + HB + aoff[rt][kt]);
                acc[0][rt] = __builtin_amdgcn_mfma_f32_16x16x32_bf16(a, bw[0][kt + 4], acc[0][rt], 0, 0, 0);
                acc[1][rt] = __builtin_amdgcn_mfma_f32_16x16x32_bf16(a, bw[1][kt + 4], acc[1][rt], 0, 0, 0);
            }
    }

    float tg[2][4], so[2][4];
    if (p == 0) {
        // sigma(i), sigma(f) -> sbuf; then stage x_{t+1}
#pragma unroll
        for (int rt = 0; rt < 2; ++rt)
#pragma unroll
            for (int r = 0; r < 4; ++r) {
                float si = sigx(acc[0][rt][r]);
                float sf = sigx(acc[1][rt][r]);
                int row = rt * 16 + lq * 4 + r;
                *(float2*)(lds + 32768 + row * 1024 + b * 128 + l15 * 8) = make_float2(si, sf);
            }
        *(uint4*)(lds + XN + xw_off) = vnext;
    } else {
#pragma unroll
        for (int rt = 0; rt < 2; ++rt)
#pragma unroll
            for (int r = 0; r < 4; ++r) {
                tg[rt][r] = tanhx(acc[0][rt][r]);
                so[rt][r] = sigx(acc[1][rt][r]);
            }
    }
    __syncthreads();  // B_sigma: sbuf visible
    if (p == 1) {
#pragma unroll
        for (int rt = 0; rt < 2; ++rt)
#pragma unroll
            for (int r = 0; r < 4; ++r) {
                int row = rt * 16 + lq * 4 + r;
                float2 s = *(const float2*)(lds + 32768 + row * 1024 + b * 128 + l15 * 8);
                float c = fmaf(s.y, cst[rt][r], s.x * tg[rt][r]);
                cst[rt][r] = c;
                float hv = so[rt][r] * tanhx(c);
                unsigned pk;
                asm("v_cvt_pk_bf16_f32 %0, %1, %2" : "=v"(pk) : "v"(hv), "v"(hv));
                int hoff = (row * 256 + (b * 16 + l15) * 2) ^ ((row & 7) << 4);
                *(unsigned short*)(lds + HN + hoff) = (unsigned short)pk;
                if (LAST) {
                    int grow = base + row;
                    if (grow < NN) out[HN_OFF + (size_t)grow * 128 + b * 16 + l15] = hv;
                }
            }
    }
}

__global__ __launch_bounds__(1024, 4) void lstm_kernel(const unsigned short* __restrict__ hp_bf,
                                                       const int* __restrict__ agg,
                                                       const unsigned short* __restrict__ Wih_b,
                                                       const unsigned short* __restrict__ Whh_b,
                                                       const unsigned short* __restrict__ Wtt,
                                                       const float* __restrict__ bsum,
                                                       float* __restrict__ out) {
    __shared__ __align__(16) unsigned char lds[65536];
    const int tid = threadIdx.x;
    const int w = tid >> 6, l = tid & 63;
    const int p = w >> 3, b = w & 7;
    const int l15 = l & 15, lq = l >> 4;
    const int base = blockIdx.x * 32;

    // B fragments: 2 gates (p*2, p*2+1) x 8 k-tiles (0..3: W_ih, 4..7: W_hh)
    short8 bw[2][8];
    const int j0 = (p * 2) * 128 + b * 16 + l15;
    const int j1 = j0 + 128;
#pragma unroll
    for (int kt = 0; kt < 4; ++kt) {
        bw[0][kt]     = *(const short8*)((const unsigned char*)Wih_b + j0 * 256 + kt * 64 + lq * 16);
        bw[1][kt]     = *(const short8*)((const unsigned char*)Wih_b + j1 * 256 + kt * 64 + lq * 16);
        bw[0][kt + 4] = *(const short8*)((const unsigned char*)Whh_b + j0 * 256 + kt * 64 + lq * 16);
        bw[1][kt + 4] = *(const short8*)((const unsigned char*)Whh_b + j1 * 256 + kt * 64 + lq * 16);
    }
    const float bi0 = bsum[j0];
    const float bi1 = bsum[j1];

    // A-fragment LDS offsets (within an 8KB buffer, swizzled)
    int aoff[2][4];
#pragma unroll
    for (int rt = 0; rt < 2; ++rt)
#pragma unroll
        for (int kt = 0; kt < 4; ++kt) {
            int arow = rt * 16 + l15;
            aoff[rt][kt] = (arow * 256 + kt * 64 + lq * 16) ^ ((arow & 7) << 4);
        }

    // gather bookkeeping (p==0 waves stage x)
    const int srow = b * 4 + lq;
    int sgrow = base + srow; if (sgrow >= NN) sgrow = NN - 1;
    const int* aggrow = agg + (size_t)sgrow * KSEQ;
    const int xw_off = (srow * 256 + l15 * 16) ^ ((srow & 7) << 4);

    f32x4 cst[2];
    cst[0] = (f32x4){0.f, 0.f, 0.f, 0.f};
    cst[1] = (f32x4){0.f, 0.f, 0.f, 0.f};

    uint4 iq = make_uint4(0u, 0u, 0u, 0u), iq2 = iq;
    if (p == 0) {
        iq = *(const uint4*)(aggrow);
        uint4 v0 = *(const uint4*)((const unsigned char*)hp_bf + (size_t)iq.x * 256 + l15 * 16);
        *(uint4*)(lds + 0 + xw_off) = v0;  // x_0 -> xbuf0
    }

    // group 0: t=0..3 (t=0 skips h-GEMM, h0=0)
    if (p == 0) iq2 = *(const uint4*)(aggrow + 4);
    lstm_step<0, true,  false>(lds, p, b, lq, l15, aoff, bw, bi0, bi1, cst, hp_bf, (int)iq.y,  xw_off, base, out);
    lstm_step<1, false, false>(lds, p, b, lq, l15, aoff, bw, bi0, bi1, cst, hp_bf, (int)iq.z,  xw_off, base, out);
    lstm_step<2, false, false>(lds, p, b, lq, l15, aoff, bw, bi0, bi1, cst, hp_bf, (int)iq.w,  xw_off, base, out);
    lstm_step<3, false, false>(lds, p, b, lq, l15, aoff, bw, bi0, bi1, cst, hp_bf, (int)iq2.x, xw_off, base, out);
    iq = iq2;

#pragma unroll 1
    for (int k = 1; k < 4; ++k) {
        if (p == 0) iq2 = *(const uint4*)(aggrow + 4 * (k + 1));
        lstm_step<0, false, false>(lds, p, b, lq, l15, aoff, bw, bi0, bi1, cst, hp_bf, (int)iq.y,  xw_off, base, out);
        lstm_step<1, false, false>(lds, p, b, lq, l15, aoff, bw, bi0, bi1, cst, hp_bf, (int)iq.z,  xw_off, base, out);
        lstm_step<2, false, false>(lds, p, b, lq, l15, aoff, bw, bi0, bi1, cst, hp_bf, (int)iq.w,  xw_off, base, out);
        lstm_step<3, false, false>(lds, p, b, lq, l15, aoff, bw, bi0, bi1, cst, hp_bf, (int)iq2.x, xw_off, base, out);
        iq = iq2;
    }

    // group 4: t=16..19; t=19 stages OWN hp row into xbuf0 for the epilogue GEMM
    lstm_step<0, false, false>(lds, p, b, lq, l15, aoff, bw, bi0, bi1, cst, hp_bf, (int)iq.y, xw_off, base, out);
    lstm_step<1, false, false>(lds, p, b, lq, l15, aoff, bw, bi0, bi1, cst, hp_bf, (int)iq.z, xw_off, base, out);
    lstm_step<2, false, false>(lds, p, b, lq, l15, aoff, bw, bi0, bi1, cst, hp_bf, (int)iq.w, xw_off, base, out);
    lstm_step<3, false, true >(lds, p, b, lq, l15, aoff, bw, bi0, bi1, cst, hp_bf, sgrow,     xw_off, base, out);

    __syncthreads();  // hbuf0 (h_20) + xbuf0 (own hp rows) visible

    if (p == 1) {
        // c_n from registers
#pragma unroll
        for (int rt = 0; rt < 2; ++rt)
#pragma unroll
            for (int r = 0; r < 4; ++r) {
                int row = rt * 16 + lq * 4 + r;
                int grow = base + row;
                if (grow < NN) out[CN_OFF + (size_t)grow * 128 + b * 16 + l15] = cst[rt][r];
            }
    } else {
        // out = elu([hp | h_n] @ W): waves 0..7 cover 128 out-cols
        const int j = b * 16 + l15;
        short8 bo[8];
#pragma unroll
        for (int kt = 0; kt < 8; ++kt)
            bo[kt] = *(const short8*)((const unsigned char*)Wtt + j * 512 + kt * 64 + lq * 16);

        f32x4 a2[2];
        a2[0] = (f32x4){0.f, 0.f, 0.f, 0.f};
        a2[1] = (f32x4){0.f, 0.f, 0.f, 0.f};
#pragma unroll
        for (int kt = 0; kt < 4; ++kt)
#pragma unroll
            for (int rt = 0; rt < 2; ++rt) {
                short8 a = *(const short8*)(lds + 0 + aoff[rt][kt]);       // hp part (xbuf0)
                a2[rt] = __builtin_amdgcn_mfma_f32_16x16x32_bf16(a, bo[kt], a2[rt], 0, 0, 0);
            }
#pragma unroll
        for (int kt = 0; kt < 4; ++kt)
#pragma unroll
            for (int rt = 0; rt < 2; ++rt) {
                short8 a = *(const short8*)(lds + 16384 + aoff[rt][kt]);   // h part (hbuf0)
                a2[rt] = __builtin_amdgcn_mfma_f32_16x16x32_bf16(a, bo[kt + 4], a2[rt], 0, 0, 0);
            }
#pragma unroll
        for (int rt = 0; rt < 2; ++rt)
#pragma unroll
            for (int r = 0; r < 4; ++r) {
                int row = rt * 16 + lq * 4 + r;
                int grow = base + row;
                if (grow < NN) {
                    float v = a2[rt][r];
                    out[(size_t)grow * 128 + j] = (v > 0.f) ? v : (exp2x(L2E * v) - 1.f);
                }
            }
    }
}

extern "C" void kernel_launch(void* const* d_in, const int* in_sizes, int n_in,
                              void* d_out, int out_size, void* d_ws, size_t ws_size,
                              hipStream_t stream) {
    (void)in_sizes; (void)n_in; (void)out_size; (void)ws_size;
    const float* h   = (const float*)d_in[0];
    const int*   agg = (const int*)d_in[1];
    const float* Wp  = (const float*)d_in[2];
    const float* W   = (const float*)d_in[3];
    const float* Wih = (const float*)d_in[4];
    const float* Whh = (const float*)d_in[5];
    const float* bih = (const float*)d_in[6];
    const float* bhh = (const float*)d_in[7];
    float* out = (float*)d_out;

    unsigned short* hp_bf = (unsigned short*)d_ws;       // 50000*128 bf16
    unsigned short* Wih_b = hp_bf + 6400000;             // 512*128
    unsigned short* Whh_b = Wih_b + 65536;               // 512*128
    unsigned short* Wpt   = Whh_b + 65536;               // 128*256 (W_past^T)
    unsigned short* Wtt   = Wpt + 32768;                 // 128*256 (W^T)
    float*          bsum  = (float*)(Wtt + 32768);       // 512

    prep_kernel<<<771, 256, 0, stream>>>(Wp, W, Wih, Whh, bih, bhh, Wih_b, Whh_b, Wpt, Wtt, bsum);
    hp_kernel<<<1563, 512, 0, stream>>>(h, Wpt, hp_bf);
    lstm_kernel<<<1563, 1024, 0, stream>>>(hp_bf, agg, Wih_b, Whh_b, Wtt, bsum, out);
}

// Round 3
// 427.414 us; speedup vs baseline: 2.1148x; 2.1148x over previous
//
#include <hip/hip_runtime.h>

#define NN 50000
#define KSEQ 20
#define HN_OFF 6400000   // N*128
#define CN_OFF 12800000  // 2*N*128

using short8 = __attribute__((ext_vector_type(8))) short;
using f32x4  = __attribute__((ext_vector_type(4))) float;

__device__ __forceinline__ unsigned short f2bf(float f) {
    unsigned int u = __float_as_uint(f);
    return (unsigned short)((u + 0x7FFFu + ((u >> 16) & 1u)) >> 16);  // RNE
}
__device__ __forceinline__ float exp2x(float x) { float r; asm("v_exp_f32 %0, %1" : "=v"(r) : "v"(x)); return r; }
__device__ __forceinline__ float rcpx(float x)  { float r; asm("v_rcp_f32 %0, %1" : "=v"(r) : "v"(x)); return r; }

#define L2E 1.4426950408889634f
__device__ __forceinline__ float sigx(float x)  { return rcpx(1.f + exp2x(-L2E * x)); }          // 1/(1+2^-xl2e)
__device__ __forceinline__ float tanhx(float x) { return fmaf(-2.f, rcpx(1.f + exp2x((2.f * L2E) * x)), 1.f); }

// ---- prep: bf16 weight packs (+transposes) and bias sum ----
__global__ void prep_kernel(const float* __restrict__ Wp, const float* __restrict__ W,
                            const float* __restrict__ Wih, const float* __restrict__ Whh,
                            const float* __restrict__ bih, const float* __restrict__ bhh,
                            unsigned short* __restrict__ Wih_b, unsigned short* __restrict__ Whh_b,
                            unsigned short* __restrict__ Wpt, unsigned short* __restrict__ Wtt,
                            float* __restrict__ bsum) {
    int tid = blockIdx.x * blockDim.x + threadIdx.x;
    if (tid < 65536) { Wih_b[tid] = f2bf(Wih[tid]); return; }
    tid -= 65536;
    if (tid < 65536) { Whh_b[tid] = f2bf(Whh[tid]); return; }
    tid -= 65536;
    if (tid < 32768) { int j = tid >> 8, k = tid & 255; Wpt[tid] = f2bf(Wp[k * 128 + j]); return; }
    tid -= 32768;
    if (tid < 32768) { int j = tid >> 8, k = tid & 255; Wtt[tid] = f2bf(W[k * 128 + j]); return; }
    tid -= 32768;
    if (tid < 512) { bsum[tid] = bih[tid] + bhh[tid]; }
}

// ---- K1: hp = bf16(h @ W_past), 32 rows/block, 8 waves (16 cols each) ----
__global__ __launch_bounds__(512, 2) void hp_kernel(const float* __restrict__ h,
                                                    const unsigned short* __restrict__ Wpt,
                                                    unsigned short* __restrict__ hp_bf) {
    __shared__ __align__(16) unsigned char smem[32 * 512];
    const int tid = threadIdx.x;
    const int w = tid >> 6, l = tid & 63;
    const int l15 = l & 15, lq = l >> 4;
    const int base = blockIdx.x * 32;

#pragma unroll
    for (int i = 0; i < 4; ++i) {
        int chunk = tid + 512 * i;
        int row = chunk >> 6, kc = chunk & 63;
        int grow = base + row;
        float4 v = make_float4(0.f, 0.f, 0.f, 0.f);
        if (grow < NN) v = *(const float4*)(h + (size_t)grow * 256 + kc * 4);
        ushort4 bv = make_ushort4(f2bf(v.x), f2bf(v.y), f2bf(v.z), f2bf(v.w));
        int off = (row * 512 + kc * 8) ^ ((row & 7) << 4);
        *(ushort4*)(smem + off) = bv;
    }
    __syncthreads();

    const int jb = w * 16 + l15;
    short8 bf[8];
#pragma unroll
    for (int kt = 0; kt < 8; ++kt)
        bf[kt] = *(const short8*)((const unsigned char*)Wpt + jb * 512 + kt * 64 + lq * 16);

    f32x4 acc[2];
    acc[0] = (f32x4){0.f, 0.f, 0.f, 0.f};
    acc[1] = (f32x4){0.f, 0.f, 0.f, 0.f};
#pragma unroll
    for (int kt = 0; kt < 8; ++kt) {
#pragma unroll
        for (int rt = 0; rt < 2; ++rt) {
            int arow = rt * 16 + l15;
            int off = (arow * 512 + kt * 64 + lq * 16) ^ ((arow & 7) << 4);
            short8 a = *(const short8*)(smem + off);
            acc[rt] = __builtin_amdgcn_mfma_f32_16x16x32_bf16(a, bf[kt], acc[rt], 0, 0, 0);
        }
    }
#pragma unroll
    for (int rt = 0; rt < 2; ++rt)
#pragma unroll
        for (int r = 0; r < 4; ++r) {
            int row = rt * 16 + lq * 4 + r;
            int grow = base + row;
            if (grow < NN) hp_bf[(size_t)grow * 128 + w * 16 + l15] = f2bf(acc[rt][r]);
        }
}

// ---- K2: fused 20-step LSTM + output GEMM. 32 rows/block, 16 waves.
// Wave pair (b, 8+b): p=0 waves own gates (i,f), p=1 waves own (g,o), 16 cols each.
// LDS (48KB): xbuf @0 (8KB), hbuf @8192 (8KB), sbuf @16384 (32KB, fp32 float2/elem).
// Single-buffered x/h: writes for t+1 occur after B_sigma (all reads of t done),
// reads of t+1 occur after B_main (all writes of t+1 done).
template<bool SKIP_H, bool LAST>
__device__ __forceinline__ void lstm_step(
    unsigned char* lds, const int p, const int lq, const int l15,
    const int off0, const short8 (&bw)[2][8],
    const float bi0, const float bi1, f32x4 (&cst)[2],
    const unsigned short* __restrict__ hp_bf, const int nextIdx,
    const int xw_off, const int sb_off, const int colj,
    const int base, float* __restrict__ out)
{
    // issue next gather BEFORE the barrier (pure global read, latency spans MFMA)
    uint4 vnext;
    if (p == 0)
        vnext = *(const uint4*)((const unsigned char*)hp_bf + (size_t)nextIdx * 256 + l15 * 16);

    __syncthreads();  // B_main: xbuf/hbuf for this step ready

    f32x4 acc[2][2];
#pragma unroll
    for (int rt = 0; rt < 2; ++rt) {
        acc[0][rt] = (f32x4){bi0, bi0, bi0, bi0};
        acc[1][rt] = (f32x4){bi1, bi1, bi1, bi1};
    }
#pragma unroll
    for (int kt = 0; kt < 4; ++kt) {
        const int xo = off0 ^ (kt << 6);
#pragma unroll
        for (int rt = 0; rt < 2; ++rt) {
            short8 a = *(const short8*)(lds + rt * 4096 + xo);  // xbuf @0
            acc[0][rt] = __builtin_amdgcn_mfma_f32_16x16x32_bf16(a, bw[0][kt], acc[0][rt], 0, 0, 0);
            acc[1][rt] = __builtin_amdgcn_mfma_f32_16x16x32_bf16(a, bw[1][kt], acc[1][rt], 0, 0, 0);
        }
    }
    if (!SKIP_H) {
#pragma unroll
        for (int kt = 0; kt < 4; ++kt) {
            const int ho = off0 ^ (kt << 6);
#pragma unroll
            for (int rt = 0; rt < 2; ++rt) {
                short8 a = *(const short8*)(lds + 8192 + rt * 4096 + ho);  // hbuf
                acc[0][rt] = __builtin_amdgcn_mfma_f32_16x16x32_bf16(a, bw[0][kt + 4], acc[0][rt], 0, 0, 0);
                acc[1][rt] = __builtin_amdgcn_mfma_f32_16x16x32_bf16(a, bw[1][kt + 4], acc[1][rt], 0, 0, 0);
            }
        }
    }

    if (p == 0) {
        // sigma(i), sigma(f) -> sbuf (fp32, exact)
#pragma unroll
        for (int rt = 0; rt < 2; ++rt)
#pragma unroll
            for (int r = 0; r < 4; ++r) {
                float si = sigx(acc[0][rt][r]);
                float sf = sigx(acc[1][rt][r]);
                *(float2*)(lds + sb_off + rt * 16384 + r * 1024) = make_float2(si, sf);
            }
    } else {
        // in-place tanh(g), sigma(o) — overlaps p0's sigma+writes
#pragma unroll
        for (int rt = 0; rt < 2; ++rt)
#pragma unroll
            for (int r = 0; r < 4; ++r) {
                acc[0][rt][r] = tanhx(acc[0][rt][r]);
                acc[1][rt][r] = sigx(acc[1][rt][r]);
            }
    }
    __syncthreads();  // B_sigma: sbuf visible; all MFMA reads of xbuf/hbuf done

    if (p == 0) {
        *(uint4*)(lds + xw_off) = vnext;  // stage x_{t+1} (or own hp row at LAST)
    } else {
#pragma unroll
        for (int rt = 0; rt < 2; ++rt)
#pragma unroll
            for (int r = 0; r < 4; ++r) {
                float2 s = *(const float2*)(lds + sb_off + rt * 16384 + r * 1024);
                float c = fmaf(s.y, cst[rt][r], s.x * acc[0][rt][r]);
                cst[rt][r] = c;
                float hv = acc[1][rt][r] * tanhx(c);
                unsigned pk;
                asm("v_cvt_pk_bf16_f32 %0, %1, %2" : "=v"(pk) : "v"(hv), "v"(hv));
                int row = rt * 16 + lq * 4 + r;
                int hoff = 8192 + ((row * 256 + colj * 2) ^ ((row & 7) << 4));
                *(unsigned short*)(lds + hoff) = (unsigned short)pk;
                if (LAST) {
                    int grow = base + row;
                    if (grow < NN) out[HN_OFF + (size_t)grow * 128 + colj] = hv;
                }
            }
    }
}

__global__ __launch_bounds__(1024, 4) void lstm_kernel(const unsigned short* __restrict__ hp_bf,
                                                       const int* __restrict__ agg,
                                                       const unsigned short* __restrict__ Wih_b,
                                                       const unsigned short* __restrict__ Whh_b,
                                                       const unsigned short* __restrict__ Wtt,
                                                       const float* __restrict__ bsum,
                                                       float* __restrict__ out) {
    __shared__ __align__(16) unsigned char lds[49152];
    const int tid = threadIdx.x;
    const int w = tid >> 6, l = tid & 63;
    const int p = w >> 3, b = w & 7;
    const int l15 = l & 15, lq = l >> 4;
    const int base = blockIdx.x * 32;
    const int colj = b * 16 + l15;

    // B fragments: 2 gates (p*2, p*2+1) x 8 k-tiles (0..3: W_ih/x, 4..7: W_hh/h)
    short8 bw[2][8];
    const int j0 = p * 256 + colj;
#pragma unroll
    for (int kt = 0; kt < 4; ++kt) {
        bw[0][kt]     = *(const short8*)((const unsigned char*)Wih_b + j0 * 256 + kt * 64 + lq * 16);
        bw[1][kt]     = *(const short8*)((const unsigned char*)Wih_b + (j0 + 128) * 256 + kt * 64 + lq * 16);
        bw[0][kt + 4] = *(const short8*)((const unsigned char*)Whh_b + j0 * 256 + kt * 64 + lq * 16);
        bw[1][kt + 4] = *(const short8*)((const unsigned char*)Whh_b + (j0 + 128) * 256 + kt * 64 + lq * 16);
    }
    const float bi0 = bsum[j0];
    const float bi1 = bsum[j0 + 128];

    // A-frag base offset (rt=0); rt=1 adds 4096 (swizzle invariant); kt XORs (kt<<6)
    const int off0 = (l15 * 256 + lq * 16) ^ ((l15 & 7) << 4);
    // sbuf element base for this lane's (col, lq); (rt,r) add compile-time imms
    const int sb_off = 16384 + lq * 4096 + colj * 8;

    // staging bookkeeping (p==0 waves gather + stage x)
    const int srow = b * 4 + lq;
    int sgrow = base + srow; if (sgrow >= NN) sgrow = NN - 1;
    const int* aggrow = agg + (size_t)sgrow * KSEQ;
    const int xw_off = (srow * 256 + l15 * 16) ^ ((srow & 7) << 4);

    f32x4 cst[2];
    cst[0] = (f32x4){0.f, 0.f, 0.f, 0.f};
    cst[1] = (f32x4){0.f, 0.f, 0.f, 0.f};

    int nidx = 0;
    if (p == 0) {
        int idx0 = aggrow[0];
        uint4 v0 = *(const uint4*)((const unsigned char*)hp_bf + (size_t)idx0 * 256 + l15 * 16);
        *(uint4*)(lds + xw_off) = v0;   // x_0 -> xbuf (visible after B_main(0))
        nidx = aggrow[1];
    }

    // t = 0 (h0 = 0: skip h-GEMM, hbuf uninitialized is fine)
    lstm_step<true, false>(lds, p, lq, l15, off0, bw, bi0, bi1, cst, hp_bf, nidx,
                           xw_off, sb_off, colj, base, out);
    if (p == 0) nidx = aggrow[2];

#pragma unroll 1
    for (int t = 1; t <= 18; ++t) {
        lstm_step<false, false>(lds, p, lq, l15, off0, bw, bi0, bi1, cst, hp_bf, nidx,
                                xw_off, sb_off, colj, base, out);
        if (p == 0) nidx = (t < 18) ? aggrow[t + 2] : sgrow;  // LAST stages own hp row
    }

    // t = 19: p1 writes h_n; p0 stages own hp row into xbuf for the epilogue
    lstm_step<false, true>(lds, p, lq, l15, off0, bw, bi0, bi1, cst, hp_bf, nidx,
                           xw_off, sb_off, colj, base, out);

    __syncthreads();  // hbuf = h_20, xbuf = own hp rows

    if (p == 1) {
        // c_n from registers
#pragma unroll
        for (int rt = 0; rt < 2; ++rt)
#pragma unroll
            for (int r = 0; r < 4; ++r) {
                int row = rt * 16 + lq * 4 + r;
                int grow = base + row;
                if (grow < NN) out[CN_OFF + (size_t)grow * 128 + colj] = cst[rt][r];
            }
    } else {
        // out = elu([hp | h_n] @ W): p0's 8 waves cover the 128 out-cols
        short8 bo[8];
#pragma unroll
        for (int kt = 0; kt < 8; ++kt)
            bo[kt] = *(const short8*)((const unsigned char*)Wtt + colj * 512 + kt * 64 + lq * 16);

        f32x4 a2[2];
        a2[0] = (f32x4){0.f, 0.f, 0.f, 0.f};
        a2[1] = (f32x4){0.f, 0.f, 0.f, 0.f};
#pragma unroll
        for (int kt = 0; kt < 4; ++kt) {
            const int xo = off0 ^ (kt << 6);
#pragma unroll
            for (int rt = 0; rt < 2; ++rt) {
                short8 a = *(const short8*)(lds + rt * 4096 + xo);          // hp (xbuf)
                a2[rt] = __builtin_amdgcn_mfma_f32_16x16x32_bf16(a, bo[kt], a2[rt], 0, 0, 0);
            }
        }
#pragma unroll
        for (int kt = 0; kt < 4; ++kt) {
            const int ho = off0 ^ (kt << 6);
#pragma unroll
            for (int rt = 0; rt < 2; ++rt) {
                short8 a = *(const short8*)(lds + 8192 + rt * 4096 + ho);   // h_n (hbuf)
                a2[rt] = __builtin_amdgcn_mfma_f32_16x16x32_bf16(a, bo[kt + 4], a2[rt], 0, 0, 0);
            }
        }
#pragma unroll
        for (int rt = 0; rt < 2; ++rt)
#pragma unroll
            for (int r = 0; r < 4; ++r) {
                int row = rt * 16 + lq * 4 + r;
                int grow = base + row;
                if (grow < NN) {
                    float v = a2[rt][r];
                    out[(size_t)grow * 128 + colj] = (v > 0.f) ? v : (exp2x(L2E * v) - 1.f);
                }
            }
    }
}

extern "C" void kernel_launch(void* const* d_in, const int* in_sizes, int n_in,
                              void* d_out, int out_size, void* d_ws, size_t ws_size,
                              hipStream_t stream) {
    (void)in_sizes; (void)n_in; (void)out_size; (void)ws_size;
    const float* h   = (const float*)d_in[0];
    const int*   agg = (const int*)d_in[1];
    const float* Wp  = (const float*)d_in[2];
    const float* W   = (const float*)d_in[3];
    const float* Wih = (const float*)d_in[4];
    const float* Whh = (const float*)d_in[5];
    const float* bih = (const float*)d_in[6];
    const float* bhh = (const float*)d_in[7];
    float* out = (float*)d_out;

    unsigned short* hp_bf = (unsigned short*)d_ws;       // 50000*128 bf16
    unsigned short* Wih_b = hp_bf + 6400000;             // 512*128
    unsigned short* Whh_b = Wih_b + 65536;               // 512*128
    unsigned short* Wpt   = Whh_b + 65536;               // 128*256 (W_past^T)
    unsigned short* Wtt   = Wpt + 32768;                 // 128*256 (W^T)
    float*          bsum  = (float*)(Wtt + 32768);       // 512

    prep_kernel<<<771, 256, 0, stream>>>(Wp, W, Wih, Whh, bih, bhh, Wih_b, Whh_b, Wpt, Wtt, bsum);
    hp_kernel<<<1563, 512, 0, stream>>>(h, Wpt, hp_bf);
    lstm_kernel<<<1563, 1024, 0, stream>>>(hp_bf, agg, Wih_b, Whh_b, Wtt, bsum, out);
}